// Round 17
// baseline (236.109 us; speedup 1.0000x reference)
//
#include <hip/hip_runtime.h>

#define B_ 2
#define S_ 2048
#define D_ 1024
#define H_ 16
#define HD_ 64
#define M_ (B_ * S_)  // 4096

typedef __bf16 bf16x8 __attribute__((ext_vector_type(8)));
typedef float f32x4 __attribute__((ext_vector_type(4)));

__device__ inline unsigned short f2bf(float f) {
    unsigned int u = __builtin_bit_cast(unsigned int, f);
    u += 0x7fffu + ((u >> 16) & 1u);
    return (unsigned short)(u >> 16);
}

// pack two f32 -> one u32 of 2x bf16 (RNE), single VALU op
__device__ inline unsigned int cvt_pk_bf16(float lo, float hi) {
    unsigned int r;
    asm("v_cvt_pk_bf16_f32 %0, %1, %2" : "=v"(r) : "v"(lo), "v"(hi));
    return r;
}

__device__ inline float fexp2(float x) { return __builtin_amdgcn_exp2f(x); }

// raw workgroup barrier with compiler memory fences on both sides
__device__ inline void barrier_fence() {
    asm volatile("" ::: "memory");
    __builtin_amdgcn_s_barrier();
    asm volatile("" ::: "memory");
}

// compiler-only memory fence: pins ISSUE ORDER of surrounding memory ops
// (vmcnt(N) counts by issue order; counted waits need pinned order)
__device__ inline void order_fence() {
    asm volatile("" ::: "memory");
}

// async global->LDS, 16 bytes/lane; LDS dest = wave-uniform base + lane*16
__device__ inline void async_ld16(const unsigned short* g, unsigned short* l) {
    __builtin_amdgcn_global_load_lds(
        (const __attribute__((address_space(1))) unsigned int*)g,
        (__attribute__((address_space(3))) unsigned int*)l, 16, 0, 0);
}

// ---------------- f32 -> bf16 convert: all 7 tensors, exact flat grid ----------------
__global__ __launch_bounds__(256) void cvt_all(
    const float* __restrict__ i0, const float* __restrict__ i1, const float* __restrict__ i2,
    const float* __restrict__ i3, const float* __restrict__ i4, const float* __restrict__ i5,
    const float* __restrict__ i6,
    unsigned short* __restrict__ o0, unsigned short* __restrict__ o1, unsigned short* __restrict__ o2,
    unsigned short* __restrict__ o3, unsigned short* __restrict__ o4, unsigned short* __restrict__ o5,
    unsigned short* __restrict__ o6) {
    int bid = blockIdx.x;
    int z, off;
    if (bid < 6144) { z = bid >> 11; off = bid & 2047; }
    else { int r = bid - 6144; z = 3 + (r >> 9); off = r & 511; }
    const float* in = (z == 0) ? i0 : (z == 1) ? i1 : (z == 2) ? i2 : (z == 3) ? i3
                     : (z == 4) ? i4 : (z == 5) ? i5 : i6;
    unsigned short* out = (z == 0) ? o0 : (z == 1) ? o1 : (z == 2) ? o2 : (z == 3) ? o3
                         : (z == 4) ? o4 : (z == 5) ? o5 : o6;
    size_t i = ((size_t)off * 256 + threadIdx.x) * 8;
    float4 v0 = *(const float4*)(in + i);
    float4 v1 = *(const float4*)(in + i + 4);
    uint4 o;
    o.x = cvt_pk_bf16(v0.x, v0.y);
    o.y = cvt_pk_bf16(v0.z, v0.w);
    o.z = cvt_pk_bf16(v1.x, v1.y);
    o.w = cvt_pk_bf16(v1.z, v1.w);
    *(uint4*)(out + i) = o;
}

// ---------------- GEMM core 128x128, BK=32, DEPTH-3 triple-buffer ----------------
// r15 lesson: in-flight DEPTH binds (load latency ~900cy > compute ~700cy/step).
// Depth-2 gave tiles ~1 step in flight; depth-3 gives ~2 steps -> fully hidden.
// Buffers cycle kt%3 (tracked incrementally, no dynamic array indexing).
// Counting: after issue(kt+3), outstanding = {kt+1,kt+2,kt+3} x4 = 12;
// vmcnt(8) drains exactly tile kt+1 (issue order pinned by barriers between
// issues; prologue issues pinned by order_fence).  Slot kt%3 restaged only
// after barrier A of the step that read it (same hazard proof as depth-2).
__device__ inline void gemm_compute(const unsigned short* __restrict__ A,
                                    const unsigned short* __restrict__ W,
                                    int K, int m0, int n0,
                                    unsigned short* smem,  // >= 49152 B: As0..2, Bs0..2
                                    f32x4 acc[4][4]) {
    const int t = threadIdx.x;
    const int lane = t & 63, wave = t >> 6;
    const int ml = lane & 15, quad = lane >> 4;
    const int wr = (wave >> 1) * 64, wc = (wave & 1) * 64;
    const int srow = lane >> 2;                        // 0..15: staging row in 16-group
    const int schunk = (lane & 3) ^ ((lane >> 4) & 3); // pre-swizzled source chunk

    const f32x4 zero = {0.f, 0.f, 0.f, 0.f};
    for (int i = 0; i < 4; i++)
        for (int j = 0; j < 4; j++) acc[i][j] = zero;

    const int niter = K >> 5;  // BK=32

    // layout (shorts): As_i at smem + i*4096, Bs_i at smem + 12288 + i*4096
    auto issue = [&](int kt, int slot) {
        unsigned short* As = smem + slot * 4096;
        unsigned short* Bs = smem + 12288 + slot * 4096;
        int k0 = kt << 5;
        for (int i = 0; i < 2; i++) {
            int r = wave * 32 + i * 16;  // rows r..r+15
            async_ld16(A + (size_t)(m0 + r + srow) * K + k0 + schunk * 8, As + r * 32);
            async_ld16(W + (size_t)(n0 + r + srow) * K + k0 + schunk * 8, Bs + r * 32);
        }
    };

    issue(0, 0);
    order_fence();
    issue(1, 1);
    order_fence();
    issue(2, 2);                                      // 12 in flight
    asm volatile("s_waitcnt vmcnt(8)" ::: "memory");  // tile 0 arrived
    barrier_fence();

    int m3 = 0;  // kt % 3, tracked incrementally
    for (int kt = 0; kt < niter; kt++) {
        unsigned short* As = smem + m3 * 4096;
        unsigned short* Bs = smem + 12288 + m3 * 4096;

        bf16x8 af[4], bfr[4];
        for (int i = 0; i < 4; i++)
            af[i] = *(const bf16x8*)(As + (wr + i * 16 + ml) * 32 + ((quad ^ (ml >> 2)) << 3));
        for (int j = 0; j < 4; j++)
            bfr[j] = *(const bf16x8*)(Bs + (wc + j * 16 + ml) * 32 + ((quad ^ (ml >> 2)) << 3));
        for (int i = 0; i < 4; i++)
            for (int j = 0; j < 4; j++)
                acc[i][j] = __builtin_amdgcn_mfma_f32_16x16x32_bf16(af[i], bfr[j], acc[i][j], 0, 0, 0);

        barrier_fence();                  // A: all waves done reading slot m3
        if (kt + 3 < niter) {
            issue(kt + 3, m3);            // restage slot m3; 12 in flight
            asm volatile("s_waitcnt vmcnt(8)" ::: "memory");  // tile kt+1 arrived
        } else if (kt + 2 < niter) {
            asm volatile("s_waitcnt vmcnt(4)" ::: "memory");  // {kt+1,kt+2} out; kt+1 arrived
        } else if (kt + 1 < niter) {
            asm volatile("s_waitcnt vmcnt(0)" ::: "memory");  // only kt+1 out
        }
        barrier_fence();                  // B: tile kt+1 visible to all waves
        m3 = (m3 == 2) ? 0 : m3 + 1;
    }
}

// ---------------- GEMM core 128x64, BK=32 — 2 blocks/CU for gemm_out (r14) ----------------
__device__ inline void gemm_compute_n64(const unsigned short* __restrict__ A,
                                        const unsigned short* __restrict__ W,
                                        int K, int m0, int n0,
                                        unsigned short* As0, unsigned short* As1,
                                        unsigned short* Bs0, unsigned short* Bs1,
                                        f32x4 acc[4][2]) {
    const int t = threadIdx.x;
    const int lane = t & 63, wave = t >> 6;
    const int ml = lane & 15, quad = lane >> 4;
    const int wr = (wave >> 1) * 64, wc = (wave & 1) * 32;
    const int srow = lane >> 2;
    const int schunk = (lane & 3) ^ ((lane >> 4) & 3);

    const f32x4 zero = {0.f, 0.f, 0.f, 0.f};
    for (int i = 0; i < 4; i++)
        for (int j = 0; j < 2; j++) acc[i][j] = zero;

    const int niter = K >> 5;  // BK=32

    auto issue = [&](int kt, unsigned short* As, unsigned short* Bs) {
        int k0 = kt << 5;
        for (int i = 0; i < 2; i++) {
            int r = wave * 32 + i * 16;
            async_ld16(A + (size_t)(m0 + r + srow) * K + k0 + schunk * 8, As + r * 32);
        }
        {
            int r = wave * 16;  // B rows r..r+15 (64 rows over 4 waves)
            async_ld16(W + (size_t)(n0 + r + srow) * K + k0 + schunk * 8, Bs + r * 32);
        }
    };

    issue(0, As0, Bs0);                               // +3
    issue(1, As1, Bs1);                               // +3 -> 6 in flight
    asm volatile("s_waitcnt vmcnt(3)" ::: "memory");  // tile 0 arrived
    barrier_fence();

    for (int kt = 0; kt < niter; kt++) {
        unsigned short* As = (kt & 1) ? As1 : As0;
        unsigned short* Bs = (kt & 1) ? Bs1 : Bs0;

        bf16x8 af[4], bfr[2];
        for (int i = 0; i < 4; i++)
            af[i] = *(const bf16x8*)(As + (wr + i * 16 + ml) * 32 + ((quad ^ (ml >> 2)) << 3));
        for (int j = 0; j < 2; j++)
            bfr[j] = *(const bf16x8*)(Bs + (wc + j * 16 + ml) * 32 + ((quad ^ (ml >> 2)) << 3));
        for (int i = 0; i < 4; i++)
            for (int j = 0; j < 2; j++)
                acc[i][j] = __builtin_amdgcn_mfma_f32_16x16x32_bf16(af[i], bfr[j], acc[i][j], 0, 0, 0);

        barrier_fence();                     // A: all waves done reading buf[kt&1]
        if (kt + 2 < niter) {
            issue(kt + 2, As, Bs);           // 6 in flight
            asm volatile("s_waitcnt vmcnt(3)" ::: "memory");  // tile kt+1 arrived
        } else {
            asm volatile("s_waitcnt vmcnt(0)" ::: "memory");  // tail drain
        }
        barrier_fence();                     // B: tile kt+1 visible to all waves
    }
}

// ---------------- QKV projection (z selects q/k/v) ----------------
// z=0: Q merged [M,1024], pre-scaled by log2(e)/8 (scores in exp2 domain).
// z=1: K merged [M,1024].  z=2: V^T [B,H,64,S].
// XCD-chunked block swizzle for A-panel L2 reuse.  49152 B dynamic LDS
// (3 staging slots; Cs epilogue 34816 B fits inside) -> still 3 blocks/CU,
// matching the 768-block grid exactly.
__global__ __launch_bounds__(256) void gemm_qkv(
    const unsigned short* __restrict__ xq, const unsigned short* __restrict__ xk,
    const unsigned short* __restrict__ xv,
    const unsigned short* __restrict__ wq, const unsigned short* __restrict__ wk,
    const unsigned short* __restrict__ wv,
    const float* __restrict__ bq, const float* __restrict__ bk, const float* __restrict__ bv,
    unsigned short* __restrict__ oq, unsigned short* __restrict__ ok,
    unsigned short* __restrict__ ov) {
    extern __shared__ __align__(16) unsigned short smem[];  // 49152 B dynamic

    // bijective XCD-chunk remap of the flat block id (grid 8 x 32 x 3 = 768)
    int f = blockIdx.x + (blockIdx.y << 3) + (blockIdx.z << 8);
    int l = (f & 7) * 96 + (f >> 3);
    int bx = l & 7, by = (l >> 3) & 31, z = l >> 8;

    const unsigned short *A, *W;
    const float* bias;
    unsigned short* out;
    if (z == 0) { A = xq; W = wq; bias = bq; out = oq; }
    else if (z == 1) { A = xk; W = wk; bias = bk; out = ok; }
    else { A = xv; W = wv; bias = bv; out = ov; }

    int m0 = by * 128, n0 = bx * 128;
    f32x4 acc[4][4];
    gemm_compute(A, W, D_, m0, n0, smem, acc);

    const int t = threadIdx.x, lane = t & 63, wave = t >> 6;
    const int ml = lane & 15, quad = lane >> 4;
    const int wr = (wave >> 1) * 64, wc = (wave & 1) * 64;

    // stage C tile as bf16 into LDS (transposed for z==2), then coalesced stores
    unsigned short* Cs = smem;  // 128 x 136 (pad) = 34816 B, reuses staging space
    // Q pre-scale: (1/sqrt(HD)) * log2(e) so attention can use raw v_exp_f32
    const float sc = (z == 0) ? 0.1803368801111204f : 1.0f;
    for (int i = 0; i < 4; i++)
        for (int j = 0; j < 4; j++) {
            int col = wc + j * 16 + ml;
            float bb = bias[n0 + col];
            for (int rg = 0; rg < 4; rg++) {
                int row = wr + i * 16 + quad * 4 + rg;
                unsigned short v = f2bf((acc[i][j][rg] + bb) * sc);
                if (z < 2) Cs[row * 136 + col] = v;
                else       Cs[col * 136 + row] = v;
            }
        }
    __syncthreads();

    const int r = t >> 1, hf = t & 1;
    if (z < 2) {
        unsigned short* dst = out + (size_t)(m0 + r) * D_ + n0 + hf * 64;
        const unsigned short* src = Cs + r * 136 + hf * 64;
        for (int i = 0; i < 8; i++)
            *(uint4*)(dst + i * 8) = *(const uint4*)(src + i * 8);
    } else {
        int n = n0 + r, h = n >> 6, d = n & 63;
        int b = m0 >> 11, s0 = m0 & 2047;
        unsigned short* dst = ov + ((size_t)((b * H_ + h) * 64 + d)) * S_ + s0 + hf * 64;
        const unsigned short* src = Cs + r * 136 + hf * 64;
        for (int i = 0; i < 8; i++)
            *(uint4*)(dst + i * 8) = *(const uint4*)(src + i * 8);
    }
}

// ---------------- output projection, 128x64 tiles, f32 epilogue ----------------
__global__ __launch_bounds__(256) void gemm_out(const unsigned short* __restrict__ A,
                                                const unsigned short* __restrict__ W,
                                                const float* __restrict__ bias,
                                                float* __restrict__ out) {
    __shared__ unsigned short As0[128 * 32], As1[128 * 32], Bs0[64 * 32], Bs1[64 * 32];

    // bijective XCD-chunk remap (grid 16 x 32 = 512 blocks = 8 XCDs x 64)
    int f = blockIdx.x + (blockIdx.y << 4);
    int l = (f & 7) * 64 + (f >> 3);
    int bx = l & 15, by = l >> 4;

    int m0 = by * 128, n0 = bx * 64;
    f32x4 acc[4][2];
    gemm_compute_n64(A, W, D_, m0, n0, As0, As1, Bs0, Bs1, acc);

    const int t = threadIdx.x, lane = t & 63, wave = t >> 6;
    const int ml = lane & 15, quad = lane >> 4;
    const int wr = (wave >> 1) * 64, wc = (wave & 1) * 32;
    for (int i = 0; i < 4; i++)
        for (int j = 0; j < 2; j++) {
            int n = n0 + wc + j * 16 + ml;
            float bb = bias[n];
            for (int rg = 0; rg < 4; rg++) {
                int m = m0 + wr + i * 16 + quad * 4 + rg;
                out[(size_t)m * D_ + n] = acc[i][j][rg] + bb;
            }
        }
}

// ---------------- flash attention, causal, S^T formulation (r9, verified) ----------------
// Q-PAIR MERGED: each block handles q-blocks (2i, 2i+1) concurrently per
// K/V tile -> per-tile fixed overhead amortized 2x.  Defer-max threshold 4.
__global__ __launch_bounds__(256, 2) void attn_kernel(const unsigned short* __restrict__ qm,
                                                      const unsigned short* __restrict__ km,
                                                      const unsigned short* __restrict__ vt,
                                                      unsigned short* __restrict__ ctx) {
    __shared__ unsigned short Ks[2][128 * 64];  // [k][hd], chunk-swizzled (^row&7)
    __shared__ unsigned short Vs[2][64 * 128];  // [d][k], chunk-swizzled (^d&15)

    const int g = blockIdx.x >> 5;
    const int ip = (g < 8) ? (15 - g) : (g - 8);  // pair id, heavy first
    const int bh = blockIdx.x & 31;
    const int b = bh >> 4, h = bh & 15;
    const size_t vbase = (size_t)bh * S_ * 64;
    const int t = threadIdx.x, lane = t & 63, wave = t >> 6;
    const int ml = lane & 15, quad = lane >> 4;
    const int lrow = lane >> 3;            // 0..7 (K staging row-in-group)
    const int gchunk = (lane & 7) ^ lrow;  // K swizzled source chunk
    const int vrow = lane >> 4;            // 0..3 (V staging row-in-group)
    const int q0 = ip * 128;               // base row of the q-pair
    const int nt = ip + 1;                 // tiles for BOTH q-blocks

    // persistent Q fragments for both q-halves (pre-scaled by log2e/8)
    bf16x8 qfA[2], qfB[2];
    {
        int qrow = q0 + wave * 16 + ml;
        const unsigned short* qp = qm + (size_t)(b * S_ + qrow) * D_ + h * 64;
        qfA[0] = *(const bf16x8*)(qp + quad * 8);
        qfA[1] = *(const bf16x8*)(qp + 32 + quad * 8);
        const unsigned short* qp2 = qp + (size_t)64 * D_;
        qfB[0] = *(const bf16x8*)(qp2 + quad * 8);
        qfB[1] = *(const bf16x8*)(qp2 + 32 + quad * 8);
    }

    // issue K tile kt into Ks[bb] (4 async instrs per wave)
    auto issue_K = [&](int kt, int bb) {
        for (int i = 0; i < 4; i++) {
            int r = wave * 32 + i * 8;  // K rows r..r+7
            async_ld16(km + (size_t)(b * S_ + kt * 128 + r + lrow) * D_ + h * 64 + gchunk * 8,
                       Ks[bb] + r * 64);
        }
    };
    // issue V tile kt into Vs[bb] (4 async instrs per wave)
    auto issue_V = [&](int kt, int bb) {
        for (int i = 0; i < 4; i++) {
            int dd = wave * 16 + i * 4;  // V rows dd..dd+3
            int d = dd + vrow;
            async_ld16(vt + vbase + (size_t)d * S_ + kt * 128 + (((lane & 15) ^ (d & 15)) << 3),
                       Vs[bb] + dd * 128);
        }
    };

    const f32x4 zero = {0.f, 0.f, 0.f, 0.f};
    f32x4 accA[4], accB[4];
    for (int j = 0; j < 4; j++) { accA[j] = zero; accB[j] = zero; }
    float mA = -INFINITY, mB = -INFINITY, lpA = 0.f, lpB = 0.f;

    issue_K(0, 0);
    issue_V(0, 0);
    asm volatile("s_waitcnt vmcnt(0)" ::: "memory");
    barrier_fence();

    for (int kt = 0; kt < nt; kt++) {
        const int buf = kt & 1;
        if (kt + 1 < nt) { issue_K(kt + 1, buf ^ 1); issue_V(kt + 1, buf ^ 1); }

        // S^T = K Q^T for both q-halves: 16 kf reads feed 32 MFMAs
        f32x4 sA[8], sB[8];
        for (int n = 0; n < 8; n++) { sA[n] = zero; sB[n] = zero; }
        __builtin_amdgcn_s_setprio(1);
        for (int n = 0; n < 8; n++)
            for (int kk = 0; kk < 2; kk++) {
                bf16x8 kf = *(const bf16x8*)(Ks[buf] + (n * 16 + ml) * 64 +
                                             (((kk * 4 + quad) ^ (ml & 7)) << 3));
                sA[n] = __builtin_amdgcn_mfma_f32_16x16x32_bf16(kf, qfA[kk], sA[n], 0, 0, 0);
                sB[n] = __builtin_amdgcn_mfma_f32_16x16x32_bf16(kf, qfB[kk], sB[n], 0, 0, 0);
            }
        __builtin_amdgcn_s_setprio(0);

        // causal mask on the shared diagonal tile
        const int qidxA = q0 + wave * 16 + ml;
        const int qidxB = qidxA + 64;
        if (kt == nt - 1) {
            for (int n = 0; n < 8; n++)
                for (int rg = 0; rg < 4; rg++) {
                    int kidx = kt * 128 + n * 16 + quad * 4 + rg;
                    if (kidx > qidxA) sA[n][rg] = -3.0e38f;
                    if (kidx > qidxB) sB[n][rg] = -3.0e38f;
                }
        }

        // lane-local max trees for both halves (independent chains -> ILP)
        float a0 = fmaxf(fmaxf(sA[0][0], sA[0][1]), fmaxf(sA[0][2], sA[0][3]));
        float a1 = fmaxf(fmaxf(sA[1][0], sA[1][1]), fmaxf(sA[1][2], sA[1][3]));
        float a2 = fmaxf(fmaxf(sA[2][0], sA[2][1]), fmaxf(sA[2][2], sA[2][3]));
        float a3 = fmaxf(fmaxf(sA[3][0], sA[3][1]), fmaxf(sA[3][2], sA[3][3]));
        float a4 = fmaxf(fmaxf(sA[4][0], sA[4][1]), fmaxf(sA[4][2], sA[4][3]));
        float a5 = fmaxf(fmaxf(sA[5][0], sA[5][1]), fmaxf(sA[5][2], sA[5][3]));
        float a6 = fmaxf(fmaxf(sA[6][0], sA[6][1]), fmaxf(sA[6][2], sA[6][3]));
        float a7 = fmaxf(fmaxf(sA[7][0], sA[7][1]), fmaxf(sA[7][2], sA[7][3]));
        float mxA = fmaxf(fmaxf(fmaxf(a0, a1), fmaxf(a2, a3)),
                          fmaxf(fmaxf(a4, a5), fmaxf(a6, a7)));
        float b0 = fmaxf(fmaxf(sB[0][0], sB[0][1]), fmaxf(sB[0][2], sB[0][3]));
        float b1 = fmaxf(fmaxf(sB[1][0], sB[1][1]), fmaxf(sB[1][2], sB[1][3]));
        float b2 = fmaxf(fmaxf(sB[2][0], sB[2][1]), fmaxf(sB[2][2], sB[2][3]));
        float b3 = fmaxf(fmaxf(sB[3][0], sB[3][1]), fmaxf(sB[3][2], sB[3][3]));
        float b4 = fmaxf(fmaxf(sB[4][0], sB[4][1]), fmaxf(sB[4][2], sB[4][3]));
        float b5 = fmaxf(fmaxf(sB[5][0], sB[5][1]), fmaxf(sB[5][2], sB[5][3]));
        float b6 = fmaxf(fmaxf(sB[6][0], sB[6][1]), fmaxf(sB[6][2], sB[6][3]));
        float b7 = fmaxf(fmaxf(sB[7][0], sB[7][1]), fmaxf(sB[7][2], sB[7][3]));
        float mxB = fmaxf(fmaxf(fmaxf(b0, b1), fmaxf(b2, b3)),
                          fmaxf(fmaxf(b4, b5), fmaxf(b6, b7)));

        // defer-max (threshold 4 -> deferred P <= 16): shuffles + rescale only
        // when some column of either half grew by > 4
        if (!__all((mxA <= mA + 4.0f) & (mxB <= mB + 4.0f))) {
            float mcA = fmaxf(mxA, __shfl_xor(mxA, 16));
            mcA = fmaxf(mcA, __shfl_xor(mcA, 32));
            mcA = fmaxf(mA, mcA);
            float alA = fexp2(mA - mcA);
            mA = mcA;
            float mcB = fmaxf(mxB, __shfl_xor(mxB, 16));
            mcB = fmaxf(mcB, __shfl_xor(mcB, 32));
            mcB = fmaxf(mB, mcB);
            float alB = fexp2(mB - mcB);
            mB = mcB;
            float aTA[4], aTB[4];
            for (int rg = 0; rg < 4; rg++) {
                aTA[rg] = __shfl(alA, quad * 4 + rg);
                aTB[rg] = __shfl(alB, quad * 4 + rg);
            }
            for (int j = 0; j < 4; j++)
                for (int rg = 0; rg < 4; rg++) {
                    accA[j][rg] *= aTA[rg];
                    accB[j][rg] *= aTB[rg];
                }
            lpA *= alA;
            lpB *= alB;
        }

        // P = exp2(s - m); per-lane l partials (reduced once in epilogue)
        for (int n = 0; n < 8; n++)
            for (int rg = 0; rg < 4; rg++) {
                sA[n][rg] = fexp2(sA[n][rg] - mA);
                sB[n][rg] = fexp2(sB[n][rg] - mB);
            }
        {
            float r0 = 0.f, r1 = 0.f;
            for (int n = 0; n < 8; n++) {
                r0 += (sA[n][0] + sA[n][1]) + (sA[n][2] + sA[n][3]);
                r1 += (sB[n][0] + sB[n][1]) + (sB[n][2] + sB[n][3]);
            }
            lpA += r0;
            lpB += r1;
        }

        // P·V for both halves: 16 vv read-pairs feed 32 MFMAs
        __builtin_amdgcn_s_setprio(1);
        for (int n2 = 0; n2 < 4; n2++) {
            union { bf16x8 v; unsigned int w[4]; } pkA, pkB;
            pkA.w[0] = cvt_pk_bf16(sA[2 * n2][0], sA[2 * n2][1]);
            pkA.w[1] = cvt_pk_bf16(sA[2 * n2][2], sA[2 * n2][3]);
            pkA.w[2] = cvt_pk_bf16(sA[2 * n2 + 1][0], sA[2 * n2 + 1][1]);
            pkA.w[3] = cvt_pk_bf16(sA[2 * n2 + 1][2], sA[2 * n2 + 1][3]);
            pkB.w[0] = cvt_pk_bf16(sB[2 * n2][0], sB[2 * n2][1]);
            pkB.w[1] = cvt_pk_bf16(sB[2 * n2][2], sB[2 * n2][3]);
            pkB.w[2] = cvt_pk_bf16(sB[2 * n2 + 1][0], sB[2 * n2 + 1][1]);
            pkB.w[3] = cvt_pk_bf16(sB[2 * n2 + 1][2], sB[2 * n2 + 1][3]);
            const int c0 = 4 * n2 + (quad >> 1);
            const int qo = (quad & 1) << 2;
            for (int j = 0; j < 4; j++) {
                int row = j * 16 + ml;  // d
                union { bf16x8 v; uint2 d2[2]; } vv;
                vv.d2[0] = *(const uint2*)(Vs[buf] + row * 128 + (((c0 ^ (row & 15)) << 3) + qo));
                vv.d2[1] = *(const uint2*)(Vs[buf] + row * 128 + ((((c0 + 2) ^ (row & 15)) << 3) + qo));
                accA[j] = __builtin_amdgcn_mfma_f32_16x16x32_bf16(pkA.v, vv.v, accA[j], 0, 0, 0);
                accB[j] = __builtin_amdgcn_mfma_f32_16x16x32_bf16(pkB.v, vv.v, accB[j], 0, 0, 0);
            }
        }
        __builtin_amdgcn_s_setprio(0);

        // one drain+barrier per tile
        asm volatile("s_waitcnt vmcnt(0)" ::: "memory");
        barrier_fence();
    }

    // epilogue: reduce l partials once, store both q-halves
    float lcA = lpA + __shfl_xor(lpA, 16);
    lcA += __shfl_xor(lcA, 32);
    float lcB = lpB + __shfl_xor(lpB, 16);
    lcB += __shfl_xor(lcB, 32);
    float invA[4], invB[4];
    for (int rg = 0; rg < 4; rg++) {
        invA[rg] = __builtin_amdgcn_rcpf(__shfl(lcA, quad * 4 + rg));
        invB[rg] = __builtin_amdgcn_rcpf(__shfl(lcB, quad * 4 + rg));
    }
    for (int j = 0; j < 4; j++) {
        int d = j * 16 + ml;
        for (int rg = 0; rg < 4; rg++) {
            int srow = q0 + wave * 16 + quad * 4 + rg;
            ctx[((size_t)(b * S_ + srow)) * D_ + h * 64 + d] = f2bf(accA[j][rg] * invA[rg]);
            ctx[((size_t)(b * S_ + srow + 64)) * D_ + h * 64 + d] = f2bf(accB[j][rg] * invB[rg]);
        }
    }
}

extern "C" void kernel_launch(void* const* d_in, const int* in_sizes, int n_in,
                              void* d_out, int out_size, void* d_ws, size_t ws_size,
                              hipStream_t stream) {
    const float* query = (const float*)d_in[0];
    const float* key_ = (const float*)d_in[1];
    const float* value = (const float*)d_in[2];
    // d_in[3] = mask: known causal, handled in-kernel
    const float* Wq = (const float*)d_in[4];
    const float* bq = (const float*)d_in[5];
    const float* Wk = (const float*)d_in[6];
    const float* bk = (const float*)d_in[7];
    const float* Wv = (const float*)d_in[8];
    const float* bv = (const float*)d_in[9];
    const float* Wo = (const float*)d_in[10];
    const float* bo = (const float*)d_in[11];
    float* out = (float*)d_out;

    const size_t XE = (size_t)M_ * D_;
    const size_t WE = (size_t)D_ * D_;
    char* ws = (char*)d_ws;
    unsigned short* xq = (unsigned short*)ws; ws += XE * 2;
    unsigned short* xk = (unsigned short*)ws; ws += XE * 2;
    unsigned short* xv = (unsigned short*)ws; ws += XE * 2;
    unsigned short* wqb = (unsigned short*)ws; ws += WE * 2;
    unsigned short* wkb = (unsigned short*)ws; ws += WE * 2;
    unsigned short* wvb = (unsigned short*)ws; ws += WE * 2;
    unsigned short* wob = (unsigned short*)ws; ws += WE * 2;
    unsigned short* qmb = (unsigned short*)ws; ws += XE * 2;  // Q merged, pre-scaled (log2e/8)
    unsigned short* kmb = (unsigned short*)ws; ws += XE * 2;  // K merged
    unsigned short* vt = (unsigned short*)ws; ws += XE * 2;   // V^T [B,H,64,S]
    unsigned short* ctx = (unsigned short*)ws; ws += XE * 2;

    // exact flat grid: 3 x 2048 (big) + 4 x 512 (weights) = 8192 blocks
    cvt_all<<<dim3(8192), 256, 0, stream>>>(
        query, key_, value, Wq, Wk, Wv, Wo,
        xq, xk, xv, wqb, wkb, wvb, wob);

    gemm_qkv<<<dim3(D_ / 128, M_ / 128, 3), 256, 49152, stream>>>(
        xq, xk, xv, wqb, wkb, wvb, bq, bk, bv, qmb, kmb, vt);

    attn_kernel<<<dim3(512), 256, 0, stream>>>(qmb, kmb, vt, ctx);

    gemm_out<<<dim3(D_ / 64, M_ / 128), 256, 0, stream>>>(ctx, wob, bo, out);
}

// Round 18
// 233.664 us; speedup vs baseline: 1.0105x; 1.0105x over previous
//
#include <hip/hip_runtime.h>

#define B_ 2
#define S_ 2048
#define D_ 1024
#define H_ 16
#define HD_ 64
#define M_ (B_ * S_)  // 4096

typedef __bf16 bf16x8 __attribute__((ext_vector_type(8)));
typedef float f32x4 __attribute__((ext_vector_type(4)));

__device__ inline unsigned short f2bf(float f) {
    unsigned int u = __builtin_bit_cast(unsigned int, f);
    u += 0x7fffu + ((u >> 16) & 1u);
    return (unsigned short)(u >> 16);
}

// pack two f32 -> one u32 of 2x bf16 (RNE), single VALU op
__device__ inline unsigned int cvt_pk_bf16(float lo, float hi) {
    unsigned int r;
    asm("v_cvt_pk_bf16_f32 %0, %1, %2" : "=v"(r) : "v"(lo), "v"(hi));
    return r;
}

__device__ inline float fexp2(float x) { return __builtin_amdgcn_exp2f(x); }

// raw workgroup barrier with compiler memory fences on both sides
__device__ inline void barrier_fence() {
    asm volatile("" ::: "memory");
    __builtin_amdgcn_s_barrier();
    asm volatile("" ::: "memory");
}

// async global->LDS, 16 bytes/lane; LDS dest = wave-uniform base + lane*16
__device__ inline void async_ld16(const unsigned short* g, unsigned short* l) {
    __builtin_amdgcn_global_load_lds(
        (const __attribute__((address_space(1))) unsigned int*)g,
        (__attribute__((address_space(3))) unsigned int*)l, 16, 0, 0);
}

// ---------------- f32 -> bf16 convert: all 7 tensors, exact flat grid ----------------
// 8 elems/thread (2x float4 -> 4x cvt_pk -> uint4 store).  Grid sized exactly:
// 3 big tensors (XE=4M elems) x 2048 blocks + 4 small (WE=1M) x 512 = 8192.
__global__ __launch_bounds__(256) void cvt_all(
    const float* __restrict__ i0, const float* __restrict__ i1, const float* __restrict__ i2,
    const float* __restrict__ i3, const float* __restrict__ i4, const float* __restrict__ i5,
    const float* __restrict__ i6,
    unsigned short* __restrict__ o0, unsigned short* __restrict__ o1, unsigned short* __restrict__ o2,
    unsigned short* __restrict__ o3, unsigned short* __restrict__ o4, unsigned short* __restrict__ o5,
    unsigned short* __restrict__ o6) {
    int bid = blockIdx.x;
    int z, off;
    if (bid < 6144) { z = bid >> 11; off = bid & 2047; }
    else { int r = bid - 6144; z = 3 + (r >> 9); off = r & 511; }
    const float* in = (z == 0) ? i0 : (z == 1) ? i1 : (z == 2) ? i2 : (z == 3) ? i3
                     : (z == 4) ? i4 : (z == 5) ? i5 : i6;
    unsigned short* out = (z == 0) ? o0 : (z == 1) ? o1 : (z == 2) ? o2 : (z == 3) ? o3
                         : (z == 4) ? o4 : (z == 5) ? o5 : o6;
    size_t i = ((size_t)off * 256 + threadIdx.x) * 8;
    float4 v0 = *(const float4*)(in + i);
    float4 v1 = *(const float4*)(in + i + 4);
    uint4 o;
    o.x = cvt_pk_bf16(v0.x, v0.y);
    o.y = cvt_pk_bf16(v0.z, v0.w);
    o.z = cvt_pk_bf16(v1.x, v1.y);
    o.w = cvt_pk_bf16(v1.z, v1.w);
    *(uint4*)(out + i) = o;
}

// ---------------- GEMM core 128x128, BK=32, counted-vmcnt DEPTH-2 (verified best) ----------------
// Two barriers per K-step, prefetch depth 2: issue(kt+2) runs after barrier A
// and is waited via vmcnt(4) only — tile kt+1's loads arrived a full step ago.
// Depth ladder measured: depth-1 = -12us (latency exposed), depth-2 = best,
// depth-3 = null.  The residual is 2-phase stage+barrier serialization, not
// in-flight depth.
__device__ inline void gemm_compute(const unsigned short* __restrict__ A,
                                    const unsigned short* __restrict__ W,
                                    int K, int m0, int n0,
                                    unsigned short* As0, unsigned short* As1,
                                    unsigned short* Bs0, unsigned short* Bs1,
                                    f32x4 acc[4][4]) {
    const int t = threadIdx.x;
    const int lane = t & 63, wave = t >> 6;
    const int ml = lane & 15, quad = lane >> 4;
    const int wr = (wave >> 1) * 64, wc = (wave & 1) * 64;
    const int srow = lane >> 2;                        // 0..15: staging row in 16-group
    const int schunk = (lane & 3) ^ ((lane >> 4) & 3); // pre-swizzled source chunk

    const f32x4 zero = {0.f, 0.f, 0.f, 0.f};
    for (int i = 0; i < 4; i++)
        for (int j = 0; j < 4; j++) acc[i][j] = zero;

    const int niter = K >> 5;  // BK=32

    auto issue = [&](int kt, unsigned short* As, unsigned short* Bs) {
        int k0 = kt << 5;
        for (int i = 0; i < 2; i++) {
            int r = wave * 32 + i * 16;  // rows r..r+15
            async_ld16(A + (size_t)(m0 + r + srow) * K + k0 + schunk * 8, As + r * 32);
            async_ld16(W + (size_t)(n0 + r + srow) * K + k0 + schunk * 8, Bs + r * 32);
        }
    };

    issue(0, As0, Bs0);                               // +4
    issue(1, As1, Bs1);                               // +4 -> 8 in flight
    asm volatile("s_waitcnt vmcnt(4)" ::: "memory");  // tile 0 arrived
    barrier_fence();

    for (int kt = 0; kt < niter; kt++) {
        unsigned short* As = (kt & 1) ? As1 : As0;
        unsigned short* Bs = (kt & 1) ? Bs1 : Bs0;

        bf16x8 af[4], bfr[4];
        for (int i = 0; i < 4; i++)
            af[i] = *(const bf16x8*)(As + (wr + i * 16 + ml) * 32 + ((quad ^ (ml >> 2)) << 3));
        for (int j = 0; j < 4; j++)
            bfr[j] = *(const bf16x8*)(Bs + (wc + j * 16 + ml) * 32 + ((quad ^ (ml >> 2)) << 3));
        for (int i = 0; i < 4; i++)
            for (int j = 0; j < 4; j++)
                acc[i][j] = __builtin_amdgcn_mfma_f32_16x16x32_bf16(af[i], bfr[j], acc[i][j], 0, 0, 0);

        barrier_fence();                     // A: all waves done reading buf[kt&1]
        if (kt + 2 < niter) {
            issue(kt + 2, As, Bs);           // restage same buf; 8 in flight
            asm volatile("s_waitcnt vmcnt(4)" ::: "memory");  // tile kt+1 arrived
        } else {
            asm volatile("s_waitcnt vmcnt(0)" ::: "memory");  // tail drain
        }
        barrier_fence();                     // B: tile kt+1 visible to all waves
    }
}

// ---------------- GEMM core 128x64, BK=32 — 2 blocks/CU for gemm_out ----------------
// Same proven depth-2 sync pattern; 3 staging loads/K-step (2 A + 1 B),
// vmcnt(3) (counted wait over a SYMMETRIC load group).
__device__ inline void gemm_compute_n64(const unsigned short* __restrict__ A,
                                        const unsigned short* __restrict__ W,
                                        int K, int m0, int n0,
                                        unsigned short* As0, unsigned short* As1,
                                        unsigned short* Bs0, unsigned short* Bs1,
                                        f32x4 acc[4][2]) {
    const int t = threadIdx.x;
    const int lane = t & 63, wave = t >> 6;
    const int ml = lane & 15, quad = lane >> 4;
    const int wr = (wave >> 1) * 64, wc = (wave & 1) * 32;
    const int srow = lane >> 2;
    const int schunk = (lane & 3) ^ ((lane >> 4) & 3);

    const f32x4 zero = {0.f, 0.f, 0.f, 0.f};
    for (int i = 0; i < 4; i++)
        for (int j = 0; j < 2; j++) acc[i][j] = zero;

    const int niter = K >> 5;  // BK=32

    // 3 loads/wave/tile: A rows wave*32..+31 (2 instr), B rows wave*16..+15 (1)
    auto issue = [&](int kt, unsigned short* As, unsigned short* Bs) {
        int k0 = kt << 5;
        for (int i = 0; i < 2; i++) {
            int r = wave * 32 + i * 16;
            async_ld16(A + (size_t)(m0 + r + srow) * K + k0 + schunk * 8, As + r * 32);
        }
        {
            int r = wave * 16;  // B rows r..r+15 (64 rows over 4 waves)
            async_ld16(W + (size_t)(n0 + r + srow) * K + k0 + schunk * 8, Bs + r * 32);
        }
    };

    issue(0, As0, Bs0);                               // +3
    issue(1, As1, Bs1);                               // +3 -> 6 in flight
    asm volatile("s_waitcnt vmcnt(3)" ::: "memory");  // tile 0 arrived
    barrier_fence();

    for (int kt = 0; kt < niter; kt++) {
        unsigned short* As = (kt & 1) ? As1 : As0;
        unsigned short* Bs = (kt & 1) ? Bs1 : Bs0;

        bf16x8 af[4], bfr[2];
        for (int i = 0; i < 4; i++)
            af[i] = *(const bf16x8*)(As + (wr + i * 16 + ml) * 32 + ((quad ^ (ml >> 2)) << 3));
        for (int j = 0; j < 2; j++)
            bfr[j] = *(const bf16x8*)(Bs + (wc + j * 16 + ml) * 32 + ((quad ^ (ml >> 2)) << 3));
        for (int i = 0; i < 4; i++)
            for (int j = 0; j < 2; j++)
                acc[i][j] = __builtin_amdgcn_mfma_f32_16x16x32_bf16(af[i], bfr[j], acc[i][j], 0, 0, 0);

        barrier_fence();                     // A: all waves done reading buf[kt&1]
        if (kt + 2 < niter) {
            issue(kt + 2, As, Bs);           // 6 in flight
            asm volatile("s_waitcnt vmcnt(3)" ::: "memory");  // tile kt+1 arrived
        } else {
            asm volatile("s_waitcnt vmcnt(0)" ::: "memory");  // tail drain
        }
        barrier_fence();                     // B: tile kt+1 visible to all waves
    }
}

// ---------------- QKV projection (z selects q/k/v) ----------------
// z=0: Q merged [M,1024], pre-scaled by log2(e)/8 (scores in exp2 domain).
// z=1: K merged [M,1024].  z=2: V^T [B,H,64,S].
// XCD-chunked block swizzle for A-panel L2 reuse.
__global__ __launch_bounds__(256) void gemm_qkv(
    const unsigned short* __restrict__ xq, const unsigned short* __restrict__ xk,
    const unsigned short* __restrict__ xv,
    const unsigned short* __restrict__ wq, const unsigned short* __restrict__ wk,
    const unsigned short* __restrict__ wv,
    const float* __restrict__ bq, const float* __restrict__ bk, const float* __restrict__ bv,
    unsigned short* __restrict__ oq, unsigned short* __restrict__ ok,
    unsigned short* __restrict__ ov) {
    extern __shared__ __align__(16) unsigned short smem[];  // 34816 B dynamic
    unsigned short* As0 = smem;                 // 128x32
    unsigned short* As1 = smem + 4096;
    unsigned short* Bs0 = smem + 8192;
    unsigned short* Bs1 = smem + 12288;

    // bijective XCD-chunk remap of the flat block id (grid 8 x 32 x 3 = 768)
    int f = blockIdx.x + (blockIdx.y << 3) + (blockIdx.z << 8);
    int l = (f & 7) * 96 + (f >> 3);
    int bx = l & 7, by = (l >> 3) & 31, z = l >> 8;

    const unsigned short *A, *W;
    const float* bias;
    unsigned short* out;
    if (z == 0) { A = xq; W = wq; bias = bq; out = oq; }
    else if (z == 1) { A = xk; W = wk; bias = bk; out = ok; }
    else { A = xv; W = wv; bias = bv; out = ov; }

    int m0 = by * 128, n0 = bx * 128;
    f32x4 acc[4][4];
    gemm_compute(A, W, D_, m0, n0, As0, As1, Bs0, Bs1, acc);

    const int t = threadIdx.x, lane = t & 63, wave = t >> 6;
    const int ml = lane & 15, quad = lane >> 4;
    const int wr = (wave >> 1) * 64, wc = (wave & 1) * 64;

    // stage C tile as bf16 into LDS (transposed for z==2), then coalesced stores
    unsigned short* Cs = smem;  // 128 x 136 (pad) = 34816 B, reuses staging space
    // Q pre-scale: (1/sqrt(HD)) * log2(e) so attention can use raw v_exp_f32
    const float sc = (z == 0) ? 0.1803368801111204f : 1.0f;
    for (int i = 0; i < 4; i++)
        for (int j = 0; j < 4; j++) {
            int col = wc + j * 16 + ml;
            float bb = bias[n0 + col];
            for (int rg = 0; rg < 4; rg++) {
                int row = wr + i * 16 + quad * 4 + rg;
                unsigned short v = f2bf((acc[i][j][rg] + bb) * sc);
                if (z < 2) Cs[row * 136 + col] = v;
                else       Cs[col * 136 + row] = v;
            }
        }
    __syncthreads();

    const int r = t >> 1, hf = t & 1;
    if (z < 2) {
        unsigned short* dst = out + (size_t)(m0 + r) * D_ + n0 + hf * 64;
        const unsigned short* src = Cs + r * 136 + hf * 64;
        for (int i = 0; i < 8; i++)
            *(uint4*)(dst + i * 8) = *(const uint4*)(src + i * 8);
    } else {
        int n = n0 + r, h = n >> 6, d = n & 63;
        int b = m0 >> 11, s0 = m0 & 2047;
        unsigned short* dst = ov + ((size_t)((b * H_ + h) * 64 + d)) * S_ + s0 + hf * 64;
        const unsigned short* src = Cs + r * 136 + hf * 64;
        for (int i = 0; i < 8; i++)
            *(uint4*)(dst + i * 8) = *(const uint4*)(src + i * 8);
    }
}

// ---------------- output projection, 128x64 tiles, f32 epilogue ----------------
__global__ __launch_bounds__(256) void gemm_out(const unsigned short* __restrict__ A,
                                                const unsigned short* __restrict__ W,
                                                const float* __restrict__ bias,
                                                float* __restrict__ out) {
    __shared__ unsigned short As0[128 * 32], As1[128 * 32], Bs0[64 * 32], Bs1[64 * 32];

    // bijective XCD-chunk remap (grid 16 x 32 = 512 blocks = 8 XCDs x 64)
    int f = blockIdx.x + (blockIdx.y << 4);
    int l = (f & 7) * 64 + (f >> 3);
    int bx = l & 15, by = l >> 4;

    int m0 = by * 128, n0 = bx * 64;
    f32x4 acc[4][2];
    gemm_compute_n64(A, W, D_, m0, n0, As0, As1, Bs0, Bs1, acc);

    const int t = threadIdx.x, lane = t & 63, wave = t >> 6;
    const int ml = lane & 15, quad = lane >> 4;
    const int wr = (wave >> 1) * 64, wc = (wave & 1) * 32;
    for (int i = 0; i < 4; i++)
        for (int j = 0; j < 2; j++) {
            int n = n0 + wc + j * 16 + ml;
            float bb = bias[n];
            for (int rg = 0; rg < 4; rg++) {
                int m = m0 + wr + i * 16 + quad * 4 + rg;
                out[(size_t)m * D_ + n] = acc[i][j][rg] + bb;
            }
        }
}

// ---------------- flash attention, causal, S^T formulation (r9, verified) ----------------
// Q-PAIR MERGED: each block handles q-blocks (2i, 2i+1) concurrently per
// K/V tile -> per-tile fixed overhead amortized 2x.  Defer-max threshold 4.
__global__ __launch_bounds__(256, 2) void attn_kernel(const unsigned short* __restrict__ qm,
                                                      const unsigned short* __restrict__ km,
                                                      const unsigned short* __restrict__ vt,
                                                      unsigned short* __restrict__ ctx) {
    __shared__ unsigned short Ks[2][128 * 64];  // [k][hd], chunk-swizzled (^row&7)
    __shared__ unsigned short Vs[2][64 * 128];  // [d][k], chunk-swizzled (^d&15)

    const int g = blockIdx.x >> 5;
    const int ip = (g < 8) ? (15 - g) : (g - 8);  // pair id, heavy first
    const int bh = blockIdx.x & 31;
    const int b = bh >> 4, h = bh & 15;
    const size_t vbase = (size_t)bh * S_ * 64;
    const int t = threadIdx.x, lane = t & 63, wave = t >> 6;
    const int ml = lane & 15, quad = lane >> 4;
    const int lrow = lane >> 3;            // 0..7 (K staging row-in-group)
    const int gchunk = (lane & 7) ^ lrow;  // K swizzled source chunk
    const int vrow = lane >> 4;            // 0..3 (V staging row-in-group)
    const int q0 = ip * 128;               // base row of the q-pair
    const int nt = ip + 1;                 // tiles for BOTH q-blocks

    // persistent Q fragments for both q-halves (pre-scaled by log2e/8)
    bf16x8 qfA[2], qfB[2];
    {
        int qrow = q0 + wave * 16 + ml;
        const unsigned short* qp = qm + (size_t)(b * S_ + qrow) * D_ + h * 64;
        qfA[0] = *(const bf16x8*)(qp + quad * 8);
        qfA[1] = *(const bf16x8*)(qp + 32 + quad * 8);
        const unsigned short* qp2 = qp + (size_t)64 * D_;
        qfB[0] = *(const bf16x8*)(qp2 + quad * 8);
        qfB[1] = *(const bf16x8*)(qp2 + 32 + quad * 8);
    }

    // issue K tile kt into Ks[bb] (4 async instrs per wave)
    auto issue_K = [&](int kt, int bb) {
        for (int i = 0; i < 4; i++) {
            int r = wave * 32 + i * 8;  // K rows r..r+7
            async_ld16(km + (size_t)(b * S_ + kt * 128 + r + lrow) * D_ + h * 64 + gchunk * 8,
                       Ks[bb] + r * 64);
        }
    };
    // issue V tile kt into Vs[bb] (4 async instrs per wave)
    auto issue_V = [&](int kt, int bb) {
        for (int i = 0; i < 4; i++) {
            int dd = wave * 16 + i * 4;  // V rows dd..dd+3
            int d = dd + vrow;
            async_ld16(vt + vbase + (size_t)d * S_ + kt * 128 + (((lane & 15) ^ (d & 15)) << 3),
                       Vs[bb] + dd * 128);
        }
    };

    const f32x4 zero = {0.f, 0.f, 0.f, 0.f};
    f32x4 accA[4], accB[4];
    for (int j = 0; j < 4; j++) { accA[j] = zero; accB[j] = zero; }
    float mA = -INFINITY, mB = -INFINITY, lpA = 0.f, lpB = 0.f;

    issue_K(0, 0);
    issue_V(0, 0);
    asm volatile("s_waitcnt vmcnt(0)" ::: "memory");
    barrier_fence();

    for (int kt = 0; kt < nt; kt++) {
        const int buf = kt & 1;
        if (kt + 1 < nt) { issue_K(kt + 1, buf ^ 1); issue_V(kt + 1, buf ^ 1); }

        // S^T = K Q^T for both q-halves: 16 kf reads feed 32 MFMAs
        f32x4 sA[8], sB[8];
        for (int n = 0; n < 8; n++) { sA[n] = zero; sB[n] = zero; }
        __builtin_amdgcn_s_setprio(1);
        for (int n = 0; n < 8; n++)
            for (int kk = 0; kk < 2; kk++) {
                bf16x8 kf = *(const bf16x8*)(Ks[buf] + (n * 16 + ml) * 64 +
                                             (((kk * 4 + quad) ^ (ml & 7)) << 3));
                sA[n] = __builtin_amdgcn_mfma_f32_16x16x32_bf16(kf, qfA[kk], sA[n], 0, 0, 0);
                sB[n] = __builtin_amdgcn_mfma_f32_16x16x32_bf16(kf, qfB[kk], sB[n], 0, 0, 0);
            }
        __builtin_amdgcn_s_setprio(0);

        // causal mask on the shared diagonal tile
        const int qidxA = q0 + wave * 16 + ml;
        const int qidxB = qidxA + 64;
        if (kt == nt - 1) {
            for (int n = 0; n < 8; n++)
                for (int rg = 0; rg < 4; rg++) {
                    int kidx = kt * 128 + n * 16 + quad * 4 + rg;
                    if (kidx > qidxA) sA[n][rg] = -3.0e38f;
                    if (kidx > qidxB) sB[n][rg] = -3.0e38f;
                }
        }

        // lane-local max trees for both halves (independent chains -> ILP)
        float a0 = fmaxf(fmaxf(sA[0][0], sA[0][1]), fmaxf(sA[0][2], sA[0][3]));
        float a1 = fmaxf(fmaxf(sA[1][0], sA[1][1]), fmaxf(sA[1][2], sA[1][3]));
        float a2 = fmaxf(fmaxf(sA[2][0], sA[2][1]), fmaxf(sA[2][2], sA[2][3]));
        float a3 = fmaxf(fmaxf(sA[3][0], sA[3][1]), fmaxf(sA[3][2], sA[3][3]));
        float a4 = fmaxf(fmaxf(sA[4][0], sA[4][1]), fmaxf(sA[4][2], sA[4][3]));
        float a5 = fmaxf(fmaxf(sA[5][0], sA[5][1]), fmaxf(sA[5][2], sA[5][3]));
        float a6 = fmaxf(fmaxf(sA[6][0], sA[6][1]), fmaxf(sA[6][2], sA[6][3]));
        float a7 = fmaxf(fmaxf(sA[7][0], sA[7][1]), fmaxf(sA[7][2], sA[7][3]));
        float mxA = fmaxf(fmaxf(fmaxf(a0, a1), fmaxf(a2, a3)),
                          fmaxf(fmaxf(a4, a5), fmaxf(a6, a7)));
        float b0 = fmaxf(fmaxf(sB[0][0], sB[0][1]), fmaxf(sB[0][2], sB[0][3]));
        float b1 = fmaxf(fmaxf(sB[1][0], sB[1][1]), fmaxf(sB[1][2], sB[1][3]));
        float b2 = fmaxf(fmaxf(sB[2][0], sB[2][1]), fmaxf(sB[2][2], sB[2][3]));
        float b3 = fmaxf(fmaxf(sB[3][0], sB[3][1]), fmaxf(sB[3][2], sB[3][3]));
        float b4 = fmaxf(fmaxf(sB[4][0], sB[4][1]), fmaxf(sB[4][2], sB[4][3]));
        float b5 = fmaxf(fmaxf(sB[5][0], sB[5][1]), fmaxf(sB[5][2], sB[5][3]));
        float b6 = fmaxf(fmaxf(sB[6][0], sB[6][1]), fmaxf(sB[6][2], sB[6][3]));
        float b7 = fmaxf(fmaxf(sB[7][0], sB[7][1]), fmaxf(sB[7][2], sB[7][3]));
        float mxB = fmaxf(fmaxf(fmaxf(b0, b1), fmaxf(b2, b3)),
                          fmaxf(fmaxf(b4, b5), fmaxf(b6, b7)));

        // defer-max (threshold 4 -> deferred P <= 16): shuffles + rescale only
        // when some column of either half grew by > 4
        if (!__all((mxA <= mA + 4.0f) & (mxB <= mB + 4.0f))) {
            float mcA = fmaxf(mxA, __shfl_xor(mxA, 16));
            mcA = fmaxf(mcA, __shfl_xor(mcA, 32));
            mcA = fmaxf(mA, mcA);
            float alA = fexp2(mA - mcA);
            mA = mcA;
            float mcB = fmaxf(mxB, __shfl_xor(mxB, 16));
            mcB = fmaxf(mcB, __shfl_xor(mcB, 32));
            mcB = fmaxf(mB, mcB);
            float alB = fexp2(mB - mcB);
            mB = mcB;
            float aTA[4], aTB[4];
            for (int rg = 0; rg < 4; rg++) {
                aTA[rg] = __shfl(alA, quad * 4 + rg);
                aTB[rg] = __shfl(alB, quad * 4 + rg);
            }
            for (int j = 0; j < 4; j++)
                for (int rg = 0; rg < 4; rg++) {
                    accA[j][rg] *= aTA[rg];
                    accB[j][rg] *= aTB[rg];
                }
            lpA *= alA;
            lpB *= alB;
        }

        // P = exp2(s - m); per-lane l partials (reduced once in epilogue)
        for (int n = 0; n < 8; n++)
            for (int rg = 0; rg < 4; rg++) {
                sA[n][rg] = fexp2(sA[n][rg] - mA);
                sB[n][rg] = fexp2(sB[n][rg] - mB);
            }
        {
            float r0 = 0.f, r1 = 0.f;
            for (int n = 0; n < 8; n++) {
                r0 += (sA[n][0] + sA[n][1]) + (sA[n][2] + sA[n][3]);
                r1 += (sB[n][0] + sB[n][1]) + (sB[n][2] + sB[n][3]);
            }
            lpA += r0;
            lpB += r1;
        }

        // P·V for both halves: 16 vv read-pairs feed 32 MFMAs
        __builtin_amdgcn_s_setprio(1);
        for (int n2 = 0; n2 < 4; n2++) {
            union { bf16x8 v; unsigned int w[4]; } pkA, pkB;
            pkA.w[0] = cvt_pk_bf16(sA[2 * n2][0], sA[2 * n2][1]);
            pkA.w[1] = cvt_pk_bf16(sA[2 * n2][2], sA[2 * n2][3]);
            pkA.w[2] = cvt_pk_bf16(sA[2 * n2 + 1][0], sA[2 * n2 + 1][1]);
            pkA.w[3] = cvt_pk_bf16(sA[2 * n2 + 1][2], sA[2 * n2 + 1][3]);
            pkB.w[0] = cvt_pk_bf16(sB[2 * n2][0], sB[2 * n2][1]);
            pkB.w[1] = cvt_pk_bf16(sB[2 * n2][2], sB[2 * n2][3]);
            pkB.w[2] = cvt_pk_bf16(sB[2 * n2 + 1][0], sB[2 * n2 + 1][1]);
            pkB.w[3] = cvt_pk_bf16(sB[2 * n2 + 1][2], sB[2 * n2 + 1][3]);
            const int c0 = 4 * n2 + (quad >> 1);
            const int qo = (quad & 1) << 2;
            for (int j = 0; j < 4; j++) {
                int row = j * 16 + ml;  // d
                union { bf16x8 v; uint2 d2[2]; } vv;
                vv.d2[0] = *(const uint2*)(Vs[buf] + row * 128 + (((c0 ^ (row & 15)) << 3) + qo));
                vv.d2[1] = *(const uint2*)(Vs[buf] + row * 128 + ((((c0 + 2) ^ (row & 15)) << 3) + qo));
                accA[j] = __builtin_amdgcn_mfma_f32_16x16x32_bf16(pkA.v, vv.v, accA[j], 0, 0, 0);
                accB[j] = __builtin_amdgcn_mfma_f32_16x16x32_bf16(pkB.v, vv.v, accB[j], 0, 0, 0);
            }
        }
        __builtin_amdgcn_s_setprio(0);

        // one drain+barrier per tile
        asm volatile("s_waitcnt vmcnt(0)" ::: "memory");
        barrier_fence();
    }

    // epilogue: reduce l partials once, store both q-halves
    float lcA = lpA + __shfl_xor(lpA, 16);
    lcA += __shfl_xor(lcA, 32);
    float lcB = lpB + __shfl_xor(lpB, 16);
    lcB += __shfl_xor(lcB, 32);
    float invA[4], invB[4];
    for (int rg = 0; rg < 4; rg++) {
        invA[rg] = __builtin_amdgcn_rcpf(__shfl(lcA, quad * 4 + rg));
        invB[rg] = __builtin_amdgcn_rcpf(__shfl(lcB, quad * 4 + rg));
    }
    for (int j = 0; j < 4; j++) {
        int d = j * 16 + ml;
        for (int rg = 0; rg < 4; rg++) {
            int srow = q0 + wave * 16 + quad * 4 + rg;
            ctx[((size_t)(b * S_ + srow)) * D_ + h * 64 + d] = f2bf(accA[j][rg] * invA[rg]);
            ctx[((size_t)(b * S_ + srow + 64)) * D_ + h * 64 + d] = f2bf(accB[j][rg] * invB[rg]);
        }
    }
}

extern "C" void kernel_launch(void* const* d_in, const int* in_sizes, int n_in,
                              void* d_out, int out_size, void* d_ws, size_t ws_size,
                              hipStream_t stream) {
    const float* query = (const float*)d_in[0];
    const float* key_ = (const float*)d_in[1];
    const float* value = (const float*)d_in[2];
    // d_in[3] = mask: known causal, handled in-kernel
    const float* Wq = (const float*)d_in[4];
    const float* bq = (const float*)d_in[5];
    const float* Wk = (const float*)d_in[6];
    const float* bk = (const float*)d_in[7];
    const float* Wv = (const float*)d_in[8];
    const float* bv = (const float*)d_in[9];
    const float* Wo = (const float*)d_in[10];
    const float* bo = (const float*)d_in[11];
    float* out = (float*)d_out;

    const size_t XE = (size_t)M_ * D_;
    const size_t WE = (size_t)D_ * D_;
    char* ws = (char*)d_ws;
    unsigned short* xq = (unsigned short*)ws; ws += XE * 2;
    unsigned short* xk = (unsigned short*)ws; ws += XE * 2;
    unsigned short* xv = (unsigned short*)ws; ws += XE * 2;
    unsigned short* wqb = (unsigned short*)ws; ws += WE * 2;
    unsigned short* wkb = (unsigned short*)ws; ws += WE * 2;
    unsigned short* wvb = (unsigned short*)ws; ws += WE * 2;
    unsigned short* wob = (unsigned short*)ws; ws += WE * 2;
    unsigned short* qmb = (unsigned short*)ws; ws += XE * 2;  // Q merged, pre-scaled (log2e/8)
    unsigned short* kmb = (unsigned short*)ws; ws += XE * 2;  // K merged
    unsigned short* vt = (unsigned short*)ws; ws += XE * 2;   // V^T [B,H,64,S]
    unsigned short* ctx = (unsigned short*)ws; ws += XE * 2;

    // exact flat grid: 3 x 2048 (big) + 4 x 512 (weights) = 8192 blocks
    cvt_all<<<dim3(8192), 256, 0, stream>>>(
        query, key_, value, Wq, Wk, Wv, Wo,
        xq, xk, xv, wqb, wkb, wvb, wob);

    gemm_qkv<<<dim3(D_ / 128, M_ / 128, 3), 256, 34816, stream>>>(
        xq, xk, xv, wqb, wkb, wvb, bq, bk, bv, qmb, kmb, vt);

    attn_kernel<<<dim3(512), 256, 0, stream>>>(qmb, kmb, vt, ctx);

    gemm_out<<<dim3(D_ / 64, M_ / 128), 256, 0, stream>>>(ctx, wob, bo, out);
}